// Round 12
// baseline (37227.640 us; speedup 1.0000x reference)
//
#include <hip/hip_runtime.h>

typedef unsigned int u32;
typedef float nf4 __attribute__((ext_vector_type(4)));
#define DEVI __device__ __forceinline__

// ---- JAX threefry2x32 (exact) ----
DEVI void tf2x32(u32 k0, u32 k1, u32 x0, u32 x1, u32& o0, u32& o1) {
  u32 ks2 = k0 ^ k1 ^ 0x1BD11BDAu;
  x0 += k0; x1 += k1;
#define TFR(r) { x0 += x1; x1 = (x1 << (r)) | (x1 >> (32 - (r))); x1 ^= x0; }
  TFR(13) TFR(15) TFR(26) TFR(6)
  x0 += k1; x1 += ks2 + 1u;
  TFR(17) TFR(29) TFR(16) TFR(24)
  x0 += ks2; x1 += k0 + 2u;
  TFR(13) TFR(15) TFR(26) TFR(6)
  x0 += k0; x1 += k1 + 3u;
  TFR(17) TFR(29) TFR(16) TFR(24)
  x0 += k1; x1 += ks2 + 4u;
  TFR(13) TFR(15) TFR(26) TFR(6)
  x0 += ks2; x1 += k0 + 5u;
#undef TFR
  o0 = x0; o1 = x1;
}

DEVI float jax_uniform(u32 k0, u32 k1, u32 idx) {
  u32 a, b; tf2x32(k0, k1, 0u, idx, a, b);
  u32 bits = a ^ b;
  return __uint_as_float((bits >> 9) | 0x3F800000u) - 1.0f;
}

DEVI float sigmoidf_(float x) { return 1.0f / (1.0f + expf(-x)); }

// ---- validated coherence primitives (R3/R4/R9/R10-proven) ----
DEVI float AL(const float* p) {
  return __hip_atomic_load((float*)p, __ATOMIC_RELAXED, __HIP_MEMORY_SCOPE_AGENT);
}
DEVI void AS(float* p, float v) {
  __hip_atomic_store(p, v, __ATOMIC_RELAXED, __HIP_MEMORY_SCOPE_AGENT);
}

// async global->LDS (IMMUTABLE data only), plain cached
typedef const __attribute__((address_space(1))) u32* gas1;
typedef __attribute__((address_space(3))) u32* las3;
DEVI void gl16n(const float* g, float* l) { __builtin_amdgcn_global_load_lds((gas1)g, (las3)l, 16, 0, 0); }
#define WAITV(N) asm volatile("s_waitcnt vmcnt(" #N ")" ::: "memory")
#define SBAR __builtin_amdgcn_sched_barrier(0)

struct KArgs {
  const float* enc_key; const float* value;
  const int* labels; const int* seqlens; const int* sos;
  const float* w_emb; const float* b_emb;
  const float* w_ih0; const float* w_hh0; const float* b_ih0; const float* b_hh0;
  const float* w_ih1; const float* w_hh1; const float* b_ih1; const float* b_hh1;
  const float* w_ih2; const float* w_hh2; const float* b_ih2; const float* b_hh2;
  const float* w_fc; const float* b_fc;
  const float* w_mlp1; const float* b_mlp1;
  const float* w_mlp2; const float* b_mlp2;
  float* out; float* ws;
};

// ws offsets (floats)
#define OF_Y0     0         // 4096
#define OF_XEMB   4096      // 256*16384
#define OF_HSB    4198400   // [3][2][512][64]
#define OF_CSB    4395008
#define OF_CTX    4591616   // [257][128][64]
#define OF_CTXQ   6696960   // [64][4][128]
#define OF_MSQ    6729728   // [64][4][2]
#define OF_QA     6730240   // [256][128][64]
#define OF_QWS    8827392   // [64][128] q exchange
#define OF_PART   8835584   // [256][32][64] gate partials
#define OF_BC     14922240  // [3][2048]
#define OF_HT     14928384  // [2][64][512]
#define OF_BAR    14993920  // 4096 ints
#define OF_QBAR   14998016  // 1024 ints
#define OF_ATT    14999040  // [256][64][512]
#define WS_TOTAL  23387648

// LDS layout (floats, 40960 total = 160 KB):
// 0      WL0 [32][224]   = 7168
// 7168   WL1 [32][256]   = 8192
// 15360  WL2 [32][256]   = 8192
// 23552  XL [256][64] (LSTM) / K-V buf0 [64][128] + buf1 (attn) / PR (PV partials)
// 39936  H2C[512] (attn qproj) -> QVb[128]+MR[32] after
// 40448  ZS [512]

// fence-free two-level grid barrier (proven)
DEVI void bar_arrive_wait(int* bar, int& ep) {
  if (threadIdx.x == 0) {
    int g = (int)(blockIdx.x & 15);
    int old = __hip_atomic_fetch_add(bar + g * 64, 1, __ATOMIC_RELAXED, __HIP_MEMORY_SCOPE_AGENT);
    if (old == ep * 16 - 1) {
      int o2 = __hip_atomic_fetch_add(bar + 1024, 1, __ATOMIC_RELAXED, __HIP_MEMORY_SCOPE_AGENT);
      if (o2 == ep * 16 - 1) {
        #pragma unroll
        for (int gg = 0; gg < 16; ++gg)
          __hip_atomic_store(bar + 2048 + gg * 64, ep, __ATOMIC_RELAXED, __HIP_MEMORY_SCOPE_AGENT);
      }
    }
    while (__hip_atomic_load(bar + 2048 + g * 64, __ATOMIC_RELAXED, __HIP_MEMORY_SCOPE_AGENT) < ep)
      __builtin_amdgcn_s_sleep(1);
  }
  __syncthreads();
  ++ep;
}
DEVI void gridbar_fast(int* bar, int& ep) {
  WAITV(0);
  __syncthreads();
  bar_arrive_wait(bar, ep);
}
DEVI void gridbar_flush(int* bar, int& ep) {
  WAITV(0);
  __syncthreads();
  if (threadIdx.x == 0) __threadfence();
  __syncthreads();
  bar_arrive_wait(bar, ep);
  if (threadIdx.x == 0) __threadfence();
  __syncthreads();
}

__global__ void bar_init_kernel(int* bar) {
  for (int i = 0; i < 5; ++i) {
    int idx = threadIdx.x + i * 1024;
    if (idx < 5120) bar[idx] = 0;
  }
}

// B=64 TK=2048 TL=256 V=64 E=256 KV=128 H=512 MH=256
__global__ __launch_bounds__(1024, 1) void dec_kernel(KArgs A) {
  const int blk = blockIdx.x;
  const int tid = threadIdx.x;
  const int lane = tid & 63;
  const int w = tid >> 6;

  float* const Y0   = A.ws + OF_Y0;
  float* const XEMB = A.ws + OF_XEMB;
  float* const HSb  = A.ws + OF_HSB;
  float* const CSb  = A.ws + OF_CSB;
  float* const CTX  = A.ws + OF_CTX;
  float* const CTXQ = A.ws + OF_CTXQ;
  float* const MSQ  = A.ws + OF_MSQ;
  float* const QA   = A.ws + OF_QA;
  float* const QWS  = A.ws + OF_QWS;
  float* const PART = A.ws + OF_PART;
  float* const BC   = A.ws + OF_BC;
  float* const HT   = A.ws + OF_HT;
  int*   const bar  = (int*)(A.ws + OF_BAR);
  int*   const qbar = (int*)(A.ws + OF_QBAR);
  float* const ATTS = A.ws + OF_ATT + (size_t)blk * 32768;

  float* const out0 = A.out;
  float* const out1 = A.out + 1048576;
  float* const out2 = A.out + 1064960;
  float* const out3 = A.out + 1081344;
  float* const out4 = A.out + 2129920;

  __shared__ __align__(16) float SMf[40960];   // 160 KB
  int ep = 1, eL = 1, eA = 1;

  const int rg = blk >> 2, kg = blk & 3;   // LSTM: row-group x k-quarter
  const int bq = rg, ch = kg;              // ATTN: batch x chunk

  u32 KA0, KA1, KB0, KB1;
  tf2x32(0u, 42u, 0u, 0u, KA0, KA1);
  tf2x32(0u, 42u, 0u, 1u, KB0, KB1);

  // ===== Prologue role work =====
  if (blk < 65) {
    int slot = blk * 1024 + tid;
    int r = slot >> 2, q = slot & 3;
    if (r < 16448) {
      bool isY0 = (r >= 16384);
      int t = 0, b, label;
      u32 key0, key1, base;
      if (!isY0) {
        t = r >> 6; b = r & 63;
        label = A.labels[t * 64 + b];
        key0 = KA0; key1 = KA1; base = (u32)(r * 64);
      } else {
        b = r - 16384;
        label = A.sos[0];
        key0 = KB0; key1 = KB1; base = (u32)(b * 64);
      }
      float sv[16];
      float mx = -3.0e38f;
      #pragma unroll
      for (int j = 0; j < 16; ++j) {
        int v = (q << 4) + j;
        float u = jax_uniform(key0, key1, base + (u32)v);
        float inner = -logf(u + 1e-10f) + 1e-10f;
        float noise = -logf(inner);
        float s = noise + ((v == label) ? 1.0f : 0.0f);
        sv[j] = s; mx = fmaxf(mx, s);
      }
      mx = fmaxf(mx, __shfl_xor(mx, 1));
      mx = fmaxf(mx, __shfl_xor(mx, 2));
      float sum = 0.f;
      #pragma unroll
      for (int j = 0; j < 16; ++j) { sv[j] = expf(sv[j] - mx); sum += sv[j]; }
      sum += __shfl_xor(sum, 1);
      sum += __shfl_xor(sum, 2);
      float inv = 1.0f / sum;
      if (!isY0) {
        #pragma unroll
        for (int j = 0; j < 16; ++j) {
          int v = (q << 4) + j;
          out3[b * 16384 + t * 64 + v] = sv[j] * inv;
        }
        if (q == 0) out2[b * 256 + t] = (float)label;
      } else {
        #pragma unroll
        for (int j = 0; j < 16; ++j) Y0[b * 64 + (q << 4) + j] = sv[j] * inv;
      }
    }
  } else if (blk < 128) {
    // zero h/c/ctx0 (contiguous 401408 at HSb)
    for (int idx = (blk - 65) * 1024 + tid; idx < 401408; idx += 63 * 1024)
      HSb[idx] = 0.f;
  } else if (blk == 255) {
    for (int idx = tid; idx < 6144; idx += 1024) {
      int l = idx >> 11, r = idx & 2047;
      const float* bi = (l == 0) ? A.b_ih0 : (l == 1) ? A.b_ih1 : A.b_ih2;
      const float* bh = (l == 0) ? A.b_hh0 : (l == 1) ? A.b_hh1 : A.b_hh2;
      BC[idx] = bi[r] + bh[r];
    }
  }
  gridbar_flush(bar, ep);

  // ===== P1: embeddings XEMB[t][e][b] (src = out3 / Y0) =====
  {
    const int t = blk;
    #pragma unroll
    for (int i = 0; i < 4; ++i) {
      int idx = tid + i * 1024;
      int b = idx >> 6, v = idx & 63;
      float sval = (t == 0) ? Y0[idx] : out3[b * 16384 + (t - 1) * 64 + v];
      SMf[b * 65 + v] = sval;
    }
    __syncthreads();
    const int b = lane;
    float* dst = XEMB + t * 16384;
    #pragma unroll 1
    for (int e0 = 0; e0 < 16; ++e0) {
      int e = w * 16 + e0;
      const float* we = A.w_emb + e * 64;
      float acc = A.b_emb[e];
      #pragma unroll 8
      for (int v = 0; v < 64; ++v) acc = fmaf(we[v], SMf[b * 65 + v], acc);
      dst[e * 64 + b] = acc;
    }
  }
  gridbar_flush(bar, ep);

  // ===== Load persistent LSTM weight slice into LDS [32 rows][K/4] =====
  {
    __syncthreads();
    #pragma unroll 1
    for (int it = 0; it < 8; ++it) {
      int idx = tid + it * 1024;
      int ri = idx >> 8, kk = idx & 255;
      if (kk < 224) {
        int R = (ri >> 3) * 512 + rg * 8 + (ri & 7);
        int gk = kg * 224 + kk;
        SMf[ri * 224 + kk] = (gk < 384) ? A.w_ih0[R * 384 + gk] : A.w_hh0[R * 512 + gk - 384];
      }
    }
    #pragma unroll 1
    for (int it = 0; it < 8; ++it) {
      int idx = tid + it * 1024;
      int ri = idx >> 8, kk = idx & 255;
      int R = (ri >> 3) * 512 + rg * 8 + (ri & 7);
      int gk = kg * 256 + kk;
      SMf[7168 + ri * 256 + kk] = (gk < 512) ? A.w_ih1[R * 512 + gk] : A.w_hh1[R * 512 + gk - 512];
    }
    #pragma unroll 1
    for (int it = 0; it < 8; ++it) {
      int idx = tid + it * 1024;
      int ri = idx >> 8, kk = idx & 255;
      int R = (ri >> 3) * 512 + rg * 8 + (ri & 7);
      int gk = kg * 256 + kk;
      SMf[15360 + ri * 256 + kk] = (gk < 512) ? A.w_ih2[R * 512 + gk] : A.w_hh2[R * 512 + gk - 512];
    }
    __syncthreads();
  }

  const int lenb = A.seqlens[bq];
  float* const XL   = SMf + 23552;
  float* const KTB0 = SMf + 23552;
  float* const KTB1 = SMf + 31744;
  float* const H2C  = SMf + 39936;
  float* const QVb  = SMf + 39936;   // aliases H2C after qproj
  float* const MRb  = SMf + 40064;   // 32 floats
  float* const ZSb  = SMf + 40448;   // 512
  float* const PRb  = SMf + 23552;   // aliases K buffers after PV

#define KST64(TILE, BUFI) { \
  const float* kp_ = A.enc_key + (size_t)bq * 262144 + (size_t)(ch * 512 + (TILE) * 64) * 128; \
  float* d_ = SMf + 23552 + (BUFI) * 8192; \
  _Pragma("unroll") for (int s_ = 0; s_ < 2; ++s_) { \
    int i_ = w * 2 + s_; \
    gl16n(kp_ + (2 * i_ + (lane >> 5)) * 128 + (lane & 31) * 4, d_ + i_ * 256); } }
#define VST64(TILE, BUFI) { \
  const float* vp_ = A.value + (size_t)bq * 262144 + (size_t)(ch * 512 + (TILE) * 64) * 128; \
  float* d_ = SMf + 23552 + (BUFI) * 8192; \
  _Pragma("unroll") for (int s_ = 0; s_ < 2; ++s_) { \
    int i_ = w * 2 + s_; \
    gl16n(vp_ + (2 * i_ + (lane >> 5)) * 128 + (lane & 31) * 4, d_ + i_ * 256); } }

  // ===== main recurrence: 4 grid barriers/step =====
  #pragma unroll 1
  for (int t = 0; t < 256; ++t) {
    const int p = t & 1;

    // ---- 3 LSTM phases: 64 rg x 4 kg, weights resident in LDS ----
    #pragma unroll 1
    for (int l = 0; l < 3; ++l) {
      const int Kq  = (l == 0) ? 224 : 256;
      const int NXR = (l == 0) ? 14 : 16;
      const int WOFF = (l == 0) ? 0 : (l == 1) ? 7168 : 15360;

      // batched x-quarter loads into registers
      float xr[16];
      if (l == 0) {
        const float* xe = XEMB + t * 16384;
        const float* ct = CTX + t * 8192;
        const float* h0 = HSb + p * 32768;
        #pragma unroll
        for (int m = 0; m < 14; ++m) {
          int idx = tid + m * 1024;
          int k = idx >> 6, b = idx & 63;
          int gk = kg * 224 + k;
          xr[m] = (gk < 256) ? xe[gk * 64 + b]
                : (gk < 384) ? AL(ct + (gk - 256) * 64 + b)
                             : AL(h0 + (gk - 384) * 64 + b);
        }
      } else {
        const float* hin = HSb + ((l - 1) * 2 + (p ^ 1)) * 32768;
        const float* hpr = HSb + (l * 2 + p) * 32768;
        #pragma unroll
        for (int m = 0; m < 16; ++m) {
          int idx = tid + m * 1024;
          int k = idx >> 6, b = idx & 63;
          int gk = kg * 256 + k;
          xr[m] = (gk < 512) ? AL(hin + gk * 64 + b) : AL(hpr + (gk - 512) * 64 + b);
        }
      }
      SBAR; WAITV(0); SBAR;
      #pragma unroll
      for (int m = 0; m < 16; ++m) {
        if (m < NXR) {
          int idx = tid + m * 1024;
          XL[(idx >> 6) * 64 + (idx & 63)] = xr[m];
        }
      }
      __syncthreads();

      // wave w computes rows 2w, 2w+1 over the k-quarter; lane = batch
      float a0 = 0.f, a1 = 0.f;
      {
        const float* wr0 = SMf + WOFF + (2 * w) * Kq;
        const float* wr1 = SMf + WOFF + (2 * w + 1) * Kq;
        const float* xb = XL + lane;
        #pragma unroll 4
        for (int k4 = 0; k4 < Kq / 4; ++k4) {
          float4 w0 = *(const float4*)(wr0 + k4 * 4);
          float4 w1 = *(const float4*)(wr1 + k4 * 4);
          float x0 = xb[(k4 * 4 + 0) * 64];
          float x1 = xb[(k4 * 4 + 1) * 64];
          float x2 = xb[(k4 * 4 + 2) * 64];
          float x3 = xb[(k4 * 4 + 3) * 64];
          a0 = fmaf(w0.w, x3, fmaf(w0.z, x2, fmaf(w0.y, x1, fmaf(w0.x, x0, a0))));
          a1 = fmaf(w1.w, x3, fmaf(w1.z, x2, fmaf(w1.y, x1, fmaf(w1.x, x0, a1))));
        }
      }
      {
        float* pb = PART + blk * 2048;
        AS(pb + (2 * w) * 64 + lane, a0);
        AS(pb + (2 * w + 1) * 64 + lane, a1);
      }
      WAITV(0);
      __syncthreads();
      // quad micro-barrier: all arrive; kg0 waits for 4
      if (tid == 0) {
        int* qc = qbar + rg * 8;
        __hip_atomic_fetch_add(qc, 1, __ATOMIC_RELAXED, __HIP_MEMORY_SCOPE_AGENT);
        if (kg == 0)
          while (__hip_atomic_load(qc, __ATOMIC_RELAXED, __HIP_MEMORY_SCOPE_AGENT) < eL * 4)
            __builtin_amdgcn_s_sleep(1);
      }
      __syncthreads();
      ++eL;
      if (kg == 0 && tid < 512) {
        int jl = tid >> 6, b = tid & 63;
        int j = rg * 8 + jl;
        const float* base = PART + rg * 4 * 2048;
        float pr[16];
        #pragma unroll
        for (int g = 0; g < 4; ++g)
          #pragma unroll
          for (int q = 0; q < 4; ++q)
            pr[g * 4 + q] = AL(base + q * 2048 + (g * 8 + jl) * 64 + b);
        float cprev = AL(CSb + (l * 2 + p) * 32768 + j * 64 + b);
        SBAR;
        float gi = pr[0] + pr[1] + pr[2] + pr[3]     + BC[l * 2048 + j];
        float gf = pr[4] + pr[5] + pr[6] + pr[7]     + BC[l * 2048 + 512 + j];
        float gG = pr[8] + pr[9] + pr[10] + pr[11]   + BC[l * 2048 + 1024 + j];
        float go = pr[12] + pr[13] + pr[14] + pr[15] + BC[l * 2048 + 1536 + j];
        float c2 = sigmoidf_(gf) * cprev + sigmoidf_(gi) * tanhf(gG);
        float h2 = sigmoidf_(go) * tanhf(c2);
        AS(CSb + (l * 2 + (p ^ 1)) * 32768 + j * 64 + b, c2);
        AS(HSb + (l * 2 + (p ^ 1)) * 32768 + j * 64 + b, h2);
        if (l == 2) AS(HT + (p ^ 1) * 32768 + b * 512 + j, h2);
      }
      if (l < 2) {
        gridbar_fast(bar, ep);
      } else {
        // drain stores, then issue K0/K1 prefetch to fly during barrier wait
        WAITV(0);
        __syncthreads();
        KST64(0, 0);
        KST64(1, 1);
        bar_arrive_wait(bar, ep);
      }
    }

    // ---- ATTN: block=(bq,ch) over 512 t'; 64-row tiles ----
    {
      // h2 -> LDS
      float h2v = 0.f;
      if (tid < 512) h2v = AL(HT + (p ^ 1) * 32768 + bq * 512 + tid);
      SBAR; WAITV(0); SBAR;
      if (tid < 512) H2C[tid] = h2v;
      __syncthreads();
      // q quarter: kv32 = tid>>5 (32 kvs), jseg = tid&31 (16 j each), w_fc direct
      {
        int kvq = ch * 32 + (tid >> 5), jseg = tid & 31;
        const float* wf = A.w_fc + kvq * 512 + jseg * 16;
        float pa = 0.f;
        #pragma unroll
        for (int i = 0; i < 16; ++i) pa = fmaf(wf[i], H2C[jseg * 16 + i], pa);
        #pragma unroll
        for (int d = 1; d < 32; d <<= 1) pa += __shfl_xor(pa, d);
        if (jseg == 0) AS(QWS + bq * 128 + kvq, pa + A.b_fc[kvq]);
      }
      WAITV(0);
      __syncthreads();
      // quad barrier #1 (q exchange)
      if (tid == 0) {
        int* qc = qbar + 512 + bq * 8;
        __hip_atomic_fetch_add(qc, 1, __ATOMIC_RELAXED, __HIP_MEMORY_SCOPE_AGENT);
        while (__hip_atomic_load(qc, __ATOMIC_RELAXED, __HIP_MEMORY_SCOPE_AGENT) < eA * 4)
          __builtin_amdgcn_s_sleep(1);
      }
      __syncthreads();
      ++eA;
      // full q -> QVb (LDS) ; ch0 writes QA
      {
        float qv = 0.f;
        if (tid < 128) qv = AL(QWS + bq * 128 + tid);
        SBAR; WAITV(0); SBAR;
        if (tid < 128) {
          QVb[tid] = qv;
          if (ch == 0) QA[t * 8192 + tid * 64 + bq] = qv;
        }
      }
      __syncthreads();
      // energy: t' = tid>>4 (64 rows/tile), seg = tid&15 (8 k each, stride 16)
      const int tl = tid >> 4, seg = tid & 15;
      float qr[8];
      #pragma unroll
      for (int i = 0; i < 8; ++i) qr[i] = QVb[seg + 16 * i];
      #pragma unroll 1
      for (int tu = 0; tu < 8; ++tu) {
        if (tu >= 2) { if (tu == 7) { WAITV(0); } else { WAITV(2); } }
        __syncthreads();
        const float* KB = (tu & 1) ? KTB1 : KTB0;
        float e = 0.f;
        #pragma unroll
        for (int i = 0; i < 8; ++i) e = fmaf(KB[tl * 128 + seg + 16 * i], qr[i], e);
        #pragma unroll
        for (int d = 1; d < 16; d <<= 1) e += __shfl_xor(e, d);
        int ta = ch * 512 + tu * 64 + tl;
        if (seg == 0) ZSb[tu * 64 + tl] = (ta < lenb) ? e : 0.0f;   // energy * mask
        __syncthreads();
        if (tu + 2 < 8) { KST64(tu + 2, (tu & 1)); }
      }
      // issue V0,V1 (overlaps softmax)
      VST64(0, 0);
      VST64(1, 1);
      // chunk softmax over 512
      float z = (tid < 512) ? ZSb[tid] : -3.0e38f;
      float mm = z;
      #pragma unroll
      for (int d = 1; d < 64; d <<= 1) mm = fmaxf(mm, __shfl_xor(mm, d));
      if (lane == 0 && w < 8) MRb[w] = mm;
      __syncthreads();
      mm = MRb[0];
      #pragma unroll
      for (int i2 = 1; i2 < 8; ++i2) mm = fmaxf(mm, MRb[i2]);
      float ex = 0.f;
      if (tid < 512) { ex = expf(z - mm); ZSb[tid] = ex; }
      float ss = ex;
      #pragma unroll
      for (int d = 1; d < 64; d <<= 1) ss += __shfl_xor(ss, d);
      if (lane == 0 && w < 8) MRb[8 + w] = ss;
      __syncthreads();
      float S = 0.f;
      #pragma unroll
      for (int i2 = 0; i2 < 8; ++i2) S += MRb[8 + i2];
      const float m_ch = mm;
      if (tid == 0) {
        AS(MSQ + bq * 8 + ch * 2, m_ch);
        AS(MSQ + bq * 8 + ch * 2 + 1, S);
      }
      // PV over 8 V tiles: kv = tid&127, tg = tid>>7 (8 t' each)
      const int kv = tid & 127, tg = tid >> 7;
      float cacc = 0.f;
      #pragma unroll 1
      for (int vt = 0; vt < 8; ++vt) {
        if (vt == 7) { WAITV(0); } else { WAITV(2); }
        __syncthreads();
        const float* VB = (vt & 1) ? KTB1 : KTB0;
        #pragma unroll
        for (int i = 0; i < 8; ++i) {
          int r = tg * 8 + i;
          cacc = fmaf(ZSb[vt * 64 + r], VB[r * 128 + kv], cacc);
        }
        __syncthreads();
        if (vt + 2 < 8) { VST64(vt + 2, (vt & 1)); }
      }
      PRb[tg * 128 + kv] = cacc;
      __syncthreads();
      float ownpart = 0.f;
      if (tid < 128) {
        float s = 0.f;
        #pragma unroll
        for (int g2 = 0; g2 < 8; ++g2) s += PRb[g2 * 128 + tid];
        ownpart = s;
        AS(CTXQ + bq * 512 + ch * 128 + tid, s);
      }
      WAITV(0);
      __syncthreads();
      // quad barrier #2 (ctx combine)
      if (tid == 0) {
        int* qc = qbar + 512 + bq * 8;
        __hip_atomic_fetch_add(qc, 1, __ATOMIC_RELAXED, __HIP_MEMORY_SCOPE_AGENT);
        while (__hip_atomic_load(qc, __ATOMIC_RELAXED, __HIP_MEMORY_SCOPE_AGENT) < eA * 4)
          __builtin_amdgcn_s_sleep(1);
      }
      __syncthreads();
      ++eA;
      if (tid < 8) MRb[16 + tid] = AL(MSQ + bq * 8 + tid);
      __syncthreads();
      float mall = fmaxf(fmaxf(MRb[16], MRb[18]), fmaxf(MRb[20], MRb[22]));
      float Z = MRb[17] * expf(MRb[16] - mall) + MRb[19] * expf(MRb[18] - mall)
              + MRb[21] * expf(MRb[20] - mall) + MRb[23] * expf(MRb[22] - mall);
      float invZ = 1.0f / Z;
      if (tid < 512)
        ATTS[(size_t)(t & 63) * 512 + tid] = ZSb[tid] * (expf(m_ch - mall) * invZ);
      if (ch == 0 && tid < 128) {
        float q1 = AL(CTXQ + bq * 512 + 128 + tid);
        float q2 = AL(CTXQ + bq * 512 + 256 + tid);
        float q3 = AL(CTXQ + bq * 512 + 384 + tid);
        float f0 = expf(MRb[16] - mall) * invZ;
        float f1 = expf(MRb[18] - mall) * invZ;
        float f2 = expf(MRb[20] - mall) * invZ;
        float f3 = expf(MRb[22] - mall) * invZ;
        AS(CTX + (t + 1) * 8192 + tid * 64 + bq,
           ownpart * f0 + q1 * f1 + q2 * f2 + q3 * f3);
      }
      // coalesced NT flush of attentions every 64 steps
      if ((t & 63) == 63) {
        __syncthreads();
        if (tid < 512) {
          float* o4 = out4 + (size_t)bq * 524288 + (size_t)(ch * 512 + tid) * 256 + (t - 63);
          const float* sst = ATTS + tid;
          #pragma unroll 4
          for (int q4i = 0; q4i < 16; ++q4i) {
            nf4 v;
            v.x = sst[(size_t)(q4i * 4 + 0) * 512];
            v.y = sst[(size_t)(q4i * 4 + 1) * 512];
            v.z = sst[(size_t)(q4i * 4 + 2) * 512];
            v.w = sst[(size_t)(q4i * 4 + 3) * 512];
            __builtin_nontemporal_store(v, (nf4*)(o4 + q4i * 4));
          }
        }
      }
    }
    gridbar_fast(bar, ep);
  }

  gridbar_flush(bar, ep);

  // ===== Epilogue: MLP head + argmax (block = one t) =====
  {
    const int t = blk;
    const int sl = w, b = lane;
    const float* qa_t = QA + t * 8192;
    const float* ct1 = CTX + (t + 1) * 8192;
    #pragma unroll
    for (int i = 0; i < 8; ++i) {
      int idx = tid + i * 1024;
      SMf[(idx >> 6) * 65 + (idx & 63)] = qa_t[idx];
      SMf[(128 + (idx >> 6)) * 65 + (idx & 63)] = ct1[idx];
    }
    __syncthreads();
    float a1[16];
    #pragma unroll
    for (int i = 0; i < 16; ++i) a1[i] = 0.f;
    const float* w1 = A.w_mlp1 + (sl * 16) * 256;
    #pragma unroll 2
    for (int k = 0; k < 256; ++k) {
      float xv = SMf[k * 65 + b];
      #pragma unroll
      for (int m2 = 0; m2 < 16; ++m2) a1[m2] = fmaf(w1[m2 * 256 + k], xv, a1[m2]);
    }
    float* ACT = SMf + 16640;
    #pragma unroll
    for (int m2 = 0; m2 < 16; ++m2) {
      float v2 = a1[m2] + A.b_mlp1[sl * 16 + m2];
      ACT[(sl * 16 + m2) * 65 + b] = (v2 >= 0.f) ? v2 : 0.9f * v2;   // LeakyReLU(0.9)
    }
    __syncthreads();
    float y[4] = {0.f, 0.f, 0.f, 0.f};
    const float* w2 = A.w_mlp2 + (sl * 4) * 256;
    #pragma unroll 2
    for (int k = 0; k < 256; ++k) {
      float xv = ACT[k * 65 + b];
      #pragma unroll
      for (int m2 = 0; m2 < 4; ++m2) y[m2] = fmaf(w2[m2 * 256 + k], xv, y[m2]);
    }
    #pragma unroll
    for (int m2 = 0; m2 < 4; ++m2) y[m2] += A.b_mlp2[sl * 4 + m2];
    *(float4*)(out0 + b * 16384 + t * 64 + sl * 4) = make_float4(y[0], y[1], y[2], y[3]);
    __syncthreads();
    float* YB = SMf + 34976;
    #pragma unroll
    for (int m2 = 0; m2 < 4; ++m2) YB[(sl * 4 + m2) * 65 + b] = y[m2];
    __syncthreads();
    if (tid < 64) {
      float best = YB[tid];
      int bi = 0;
      #pragma unroll 1
      for (int v = 1; v < 64; ++v) {
        float val = YB[v * 65 + tid];
        if (val > best) { best = val; bi = v; }   // first-occurrence argmax
      }
      out1[tid * 256 + t] = (float)bi;
    }
  }
}

extern "C" void kernel_launch(void* const* d_in, const int* in_sizes, int n_in,
                              void* d_out, int out_size, void* d_ws, size_t ws_size,
                              hipStream_t stream) {
  if (ws_size < (size_t)WS_TOTAL * 4) return;   // ~93.6 MB scratch
  KArgs a;
  a.enc_key = (const float*)d_in[0];
  a.value   = (const float*)d_in[1];
  a.labels  = (const int*)d_in[2];
  a.seqlens = (const int*)d_in[3];
  a.sos     = (const int*)d_in[4];
  a.w_emb  = (const float*)d_in[6];  a.b_emb  = (const float*)d_in[7];
  a.w_ih0  = (const float*)d_in[8];  a.w_hh0  = (const float*)d_in[9];
  a.b_ih0  = (const float*)d_in[10]; a.b_hh0  = (const float*)d_in[11];
  a.w_ih1  = (const float*)d_in[12]; a.w_hh1  = (const float*)d_in[13];
  a.b_ih1  = (const float*)d_in[14]; a.b_hh1  = (const float*)d_in[15];
  a.w_ih2  = (const float*)d_in[16]; a.w_hh2  = (const float*)d_in[17];
  a.b_ih2  = (const float*)d_in[18]; a.b_hh2  = (const float*)d_in[19];
  a.w_fc   = (const float*)d_in[20]; a.b_fc   = (const float*)d_in[21];
  a.w_mlp1 = (const float*)d_in[22]; a.b_mlp1 = (const float*)d_in[23];
  a.w_mlp2 = (const float*)d_in[24]; a.b_mlp2 = (const float*)d_in[25];
  a.out = (float*)d_out;
  a.ws  = (float*)d_ws;

  int* bar = (int*)((float*)d_ws + OF_BAR);
  hipLaunchKernelGGL(bar_init_kernel, dim3(1), dim3(1024), 0, stream, bar);

  void* args[] = { (void*)&a };
  hipLaunchCooperativeKernel(reinterpret_cast<void*>(dec_kernel),
                             dim3(256), dim3(1024), args, 0, stream);
}